// Round 1
// baseline (284.851 us; speedup 1.0000x reference)
//
#include <hip/hip_runtime.h>

#define BB 8
#define NN 1024
#define CC 768
#define OO 768
#define RR 16
#define MM (BB*NN)      /* 8192  */
#define KK (CC*RR)      /* 12288 */
#define BM 128
#define BO 128
#define BK 64
#define KTILES (KK/BK)  /* 192 */

typedef __bf16 bf16x8 __attribute__((ext_vector_type(8)));
typedef float  f32x4  __attribute__((ext_vector_type(4)));

__device__ static __forceinline__ void gl_lds16(const void* g, void* l) {
    __builtin_amdgcn_global_load_lds(
        (const __attribute__((address_space(1))) void*)g,
        (__attribute__((address_space(3))) void*)l,
        16, 0, 0);
}

// ---- prep: weight fp32 -> bf16 (ws), and bias_term[n,o] = coef[n,:]·bias[o,:] ----
__global__ __launch_bounds__(256) void k_prep(const float* __restrict__ w,
                                              const float* __restrict__ coef,
                                              const float* __restrict__ bias,
                                              __bf16* __restrict__ wbf,
                                              float* __restrict__ bterm) {
    long id = blockIdx.x;
    if (id < 4608) {                       // convert 9.44M weights, 8/thread
        long u = (id * 256 + threadIdx.x) * 8;
        float4 a = *(const float4*)(w + u);
        float4 b = *(const float4*)(w + u + 4);
        bf16x8 v = {(__bf16)a.x, (__bf16)a.y, (__bf16)a.z, (__bf16)a.w,
                    (__bf16)b.x, (__bf16)b.y, (__bf16)b.z, (__bf16)b.w};
        *(bf16x8*)(wbf + u) = v;
    } else {                               // bias_term: 1024*768 dots of length 16
        int i = (int)(id - 4608) * 256 + threadIdx.x;
        int n = i / OO, o = i - n * OO;
        float s = 0.f;
#pragma unroll
        for (int r = 0; r < RR; ++r) s += coef[n * RR + r] * bias[o * RR + r];
        bterm[i] = s;
    }
}

// ---- main GEMM: out[m,o] = sum_k A[m,k]*W[o,k] + bterm[n,o] ----
// A built on the fly: A[m, c*16+r] = x[m,c] * coef[n,r]
__global__ __launch_bounds__(256, 2) void k_gemm(const float* __restrict__ x,
                                                 const float* __restrict__ coef,
                                                 const __bf16* __restrict__ wbf,
                                                 const float* __restrict__ bterm,
                                                 float* __restrict__ out) {
    __shared__ __bf16 lA[BM * BK];   // row-major, 8 chunks of 16B per row, XOR-swizzled
    __shared__ __bf16 lB[BO * BK];

    const int tid = threadIdx.x;

    // XCD-aware block swizzle: all blocks on one XCD share the same o-tile (3MB W col fits 4MB L2)
    int id    = blockIdx.x;          // 0..383
    int xcd   = id & 7;
    int slot  = id >> 3;             // 0..47
    int otile = slot >> 3;           // 0..5
    int mtile = xcd * 8 + (slot & 7);// 0..63
    const int m0 = mtile * BM, o0 = otile * BO;

    // ---- A-build mapping: thread -> (row m, c-pair) ----
    const int am     = tid & 127;
    const int ahalf  = tid >> 7;            // 0/1 -> c_local {0,1} or {2,3}
    const int m_glob = m0 + am;
    const int n_idx  = m_glob & (NN - 1);
    const float* xrow = x + (long)m_glob * CC;

    float cf[16];
#pragma unroll
    for (int r = 0; r < 16; r += 4) {
        float4 t4 = *(const float4*)(coef + n_idx * RR + r);
        cf[r] = t4.x; cf[r + 1] = t4.y; cf[r + 2] = t4.z; cf[r + 3] = t4.w;
    }

    // ---- wave / fragment mapping (m97 gemm_bt layout) ----
    const int lane = tid & 63, wave = tid >> 6;
    const int wm = (wave & 1) * 64, wo = (wave >> 1) * 64;
    const int lrow = lane & 15, quad = lane >> 4;

    f32x4 acc[4][4] = {};

    float2 x2 = *(const float2*)(xrow + 2 * ahalf);   // prefetch kt=0

#pragma unroll 1
    for (int kt = 0; kt < KTILES; ++kt) {
        // --- stage B (async DMA, global-side XOR swizzle) ---
#pragma unroll
        for (int s = 0; s < 4; ++s) {
            int u = s * 256 + tid;
            int row = u >> 3, cl = u & 7;
            int g = cl ^ (row & 7);   // logical chunk stored at LDS chunk cl
            const __bf16* gp = wbf + (long)(o0 + row) * KK + kt * BK + g * 8;
            gl_lds16(gp, ((char*)lB) + u * 16);
        }
        // --- prefetch x for next tile (latency overlapped with A build) ---
        float2 x2n = x2;
        if (kt + 1 < KTILES) x2n = *(const float2*)(xrow + (kt + 1) * 4 + 2 * ahalf);
        // --- build A tile: 2 c's x 16 r's -> 4 swizzled 16B chunks ---
#pragma unroll
        for (int ci = 0; ci < 2; ++ci) {
            float xv = (ci == 0) ? x2.x : x2.y;
            int c_local = 2 * ahalf + ci;
#pragma unroll
            for (int rh = 0; rh < 2; ++rh) {
                bf16x8 v;
#pragma unroll
                for (int j = 0; j < 8; ++j) v[j] = (__bf16)(xv * cf[rh * 8 + j]);
                int kb  = c_local * 2 + rh;        // logical chunk 0..7
                int kbs = kb ^ (am & 7);           // swizzled slot
                *(bf16x8*)(&lA[am * BK + kbs * 8]) = v;
            }
        }
        x2 = x2n;
        __syncthreads();   // drains B-DMA (vmcnt) + A ds_writes (lgkmcnt)

        // --- compute: 2 k-steps x 16 MFMA ---
#pragma unroll
        for (int ks = 0; ks < 2; ++ks) {
            bf16x8 af[4], bfr[4];
            int kb = ks * 4 + quad;
#pragma unroll
            for (int im = 0; im < 4; ++im) {
                int row = wm + im * 16 + lrow;
                af[im] = *(const bf16x8*)(&lA[row * BK + (kb ^ (row & 7)) * 8]);
            }
#pragma unroll
            for (int io = 0; io < 4; ++io) {
                int row = wo + io * 16 + lrow;
                bfr[io] = *(const bf16x8*)(&lB[row * BK + (kb ^ (row & 7)) * 8]);
            }
#pragma unroll
            for (int im = 0; im < 4; ++im)
#pragma unroll
                for (int io = 0; io < 4; ++io)
                    acc[im][io] = __builtin_amdgcn_mfma_f32_16x16x32_bf16(
                        af[im], bfr[io], acc[im][io], 0, 0, 0);
        }
        __syncthreads();   // protect LDS before next stage
    }

    // ---- epilogue: D col=lane&15 (o), row=(lane>>4)*4+reg (m); add bias_term ----
    const int nbase = m0 & (NN - 1);
#pragma unroll
    for (int im = 0; im < 4; ++im) {
#pragma unroll
        for (int io = 0; io < 4; ++io) {
            int o = o0 + wo + io * 16 + lrow;
#pragma unroll
            for (int r = 0; r < 4; ++r) {
                int moff = wm + im * 16 + quad * 4 + r;
                long m = m0 + moff;
                out[m * OO + o] = acc[im][io][r] + bterm[(nbase + moff) * OO + o];
            }
        }
    }
}

// ---- fallback if workspace too small (correctness-only) ----
__global__ void k_naive(const float* __restrict__ x, const float* __restrict__ coef,
                        const float* __restrict__ w, const float* __restrict__ bias,
                        float* __restrict__ out) {
    long i = (long)blockIdx.x * 256 + threadIdx.x;
    if (i >= (long)MM * OO) return;
    int o = (int)(i % OO);
    long m = i / OO;
    int n = (int)(m & (NN - 1));
    float cf[16];
#pragma unroll
    for (int r = 0; r < 16; ++r) cf[r] = coef[n * RR + r];
    const float* xr = x + m * CC;
    const float* wr = w + (long)o * CC * RR;
    float s = 0.f;
    for (int c = 0; c < CC; ++c) {
        float t = 0.f;
#pragma unroll
        for (int r = 0; r < 16; ++r) t += cf[r] * wr[c * RR + r];
        s += xr[c] * t;
    }
    float bs = 0.f;
#pragma unroll
    for (int r = 0; r < 16; ++r) bs += cf[r] * bias[o * RR + r];
    out[i] = s + bs;
}

extern "C" void kernel_launch(void* const* d_in, const int* in_sizes, int n_in,
                              void* d_out, int out_size, void* d_ws, size_t ws_size,
                              hipStream_t stream) {
    const float* x    = (const float*)d_in[0];
    const float* coef = (const float*)d_in[1];
    const float* w    = (const float*)d_in[2];
    const float* bias = (const float*)d_in[3];
    float* out = (float*)d_out;

    const size_t wbf_bytes = (size_t)OO * KK * sizeof(__bf16);   // 18,874,368
    const size_t bt_bytes  = (size_t)NN * OO * sizeof(float);    //  3,145,728

    if (ws_size >= wbf_bytes + bt_bytes) {
        __bf16* wbf  = (__bf16*)d_ws;
        float*  btrm = (float*)((char*)d_ws + wbf_bytes);
        k_prep<<<7680, 256, 0, stream>>>(w, coef, bias, wbf, btrm);
        k_gemm<<<384, 256, 0, stream>>>(x, coef, wbf, btrm, out);
    } else {
        k_naive<<<(int)(((long)MM * OO + 255) / 256), 256, 0, stream>>>(x, coef, w, bias, out);
    }
}